// Round 19
// baseline (503.828 us; speedup 1.0000x reference)
//
#include <hip/hip_runtime.h>

// VectorQuantizer: z [16,4096,256] f32, embedding [1024,256] f32
// out (f32, flat): z_q[16777216] | vq_loss[1] | commitment_loss[1] | idxs-as-float[65536]

#define ROWS 65536
#define EDIM 256
#define NEMB 1024
#define OUT_VQ  16777216
#define OUT_CM  16777217
#define OUT_IDX 16777218
#define MARGIN  0.8f

typedef __attribute__((ext_vector_type(8))) short bf16x8;
typedef __attribute__((ext_vector_type(4))) float f32x4;

__device__ inline unsigned short f2bf(float x) {
  unsigned u = __builtin_bit_cast(unsigned, x);
  unsigned r = (u + 0x7fff + ((u >> 16) & 1)) >> 16;
  return (unsigned short)r;
}
__device__ inline void gload_lds16(const void* g, void* l) {
  __builtin_amdgcn_global_load_lds((const __attribute__((address_space(1))) unsigned int*)g,
                                   (__attribute__((address_space(3))) unsigned int*)l,
                                   16, 0, 0);
}

// ---------------- zprep (fused): 0-8191 zsplit | 8192-8255 etrans | 8256-8259 eprep ----
__global__ __launch_bounds__(256) void zprep_kernel(const float* __restrict__ z,
                                                    unsigned short* __restrict__ zhi,
                                                    const float* __restrict__ emb,
                                                    unsigned short* __restrict__ ehi,
                                                    float* __restrict__ e2,
                                                    int* __restrict__ cnt,
                                                    float* __restrict__ embT) {
  __shared__ float tile[64][65];
  const int bid = blockIdx.x;
  if (bid < 8192) {
    // zsplit: z -> bf16 hi (validated body)
    size_t gid = (size_t)bid * 256 + threadIdx.x;
    const float4* z4 = (const float4*)z;
    float4 v0 = z4[gid * 2];
    float4 v1 = z4[gid * 2 + 1];
    uint4 ph;
    ph.x = (unsigned)f2bf(v0.x) | ((unsigned)f2bf(v0.y) << 16);
    ph.y = (unsigned)f2bf(v0.z) | ((unsigned)f2bf(v0.w) << 16);
    ph.z = (unsigned)f2bf(v1.x) | ((unsigned)f2bf(v1.y) << 16);
    ph.w = (unsigned)f2bf(v1.z) | ((unsigned)f2bf(v1.w) << 16);
    ((uint4*)zhi)[gid] = ph;
  } else if (bid < 8256) {
    // etrans: embT[k][c] = emb[c][k], 64x64 LDS tiles (validated body)
    const int bb = bid - 8192;
    const int bc = bb & 15;
    const int bk = bb >> 4;
    const int c0 = bc * 64, k0 = bk * 64;
    const int r = threadIdx.x >> 2;
    const int q = threadIdx.x & 3;
    #pragma unroll
    for (int j = 0; j < 4; ++j) {
      int kq = q + j * 4;
      float4 v = *(const float4*)&emb[(size_t)(c0 + r) * EDIM + k0 + kq * 4];
      tile[r][kq * 4 + 0] = v.x; tile[r][kq * 4 + 1] = v.y;
      tile[r][kq * 4 + 2] = v.z; tile[r][kq * 4 + 3] = v.w;
    }
    __syncthreads();
    #pragma unroll
    for (int j = 0; j < 4; ++j) {
      int cq = q + j * 4;
      float4 w;
      w.x = tile[cq * 4 + 0][r]; w.y = tile[cq * 4 + 1][r];
      w.z = tile[cq * 4 + 2][r]; w.w = tile[cq * 4 + 3][r];
      *(float4*)&embT[(size_t)(k0 + r) * NEMB + c0 + cq * 4] = w;
    }
  } else {
    // eprep: emb -> bf16 hi, e2 (R1 rounding order), counters reset (validated body)
    int c = (bid - 8256) * 256 + threadIdx.x;
    if (c == 0) { cnt[0] = 0; cnt[1] = 0; }   // cnt[1] = gather-done counter
    const float4* p = (const float4*)(emb + (size_t)c * EDIM);
    unsigned short* eh = ehi + (size_t)c * EDIM;
    float s = 0.f;
    #pragma unroll 8
    for (int j = 0; j < EDIM / 4; ++j) {
      float4 v = p[j];
      s += v.x * v.x; s += v.y * v.y; s += v.z * v.z; s += v.w * v.w;
      uint2 ph;
      ph.x = (unsigned)f2bf(v.x) | ((unsigned)f2bf(v.y) << 16);
      ph.y = (unsigned)f2bf(v.z) | ((unsigned)f2bf(v.w) << 16);
      *(uint2*)(eh + j * 4) = ph;
    }
    e2[c] = s;
  }
}

// ---------------- barrier-free strip argmax, mantissa-packed top-2 keys (validated) -----
__global__ __launch_bounds__(512) void argmax_kernel(
    const unsigned short* __restrict__ zhi, const unsigned short* __restrict__ ehi,
    const float* __restrict__ e2, float2* __restrict__ gtop) {
  __shared__ short Bs[128 * 256];   // 64 KB

  const int tid  = threadIdx.x;
  const int w    = tid >> 6;      // wave 0..7
  const int lane = tid & 63;
  const int q    = lane >> 4;     // 0..3
  const int lr   = lane & 15;
  const int b = blockIdx.x;
  const int mchunk = b & 63;
  const int nstrip = b >> 6;
  const int nc = nstrip * 128;
  const int rbase0 = mchunk * 1024;

  // ---- stage B once: instr j writes rows {w*16+j*2, +1} linearly; src pre-swizzled ----
  {
    const int qq = lane & 31;            // quad within row
    const int rj = lane >> 5;            // row within pair
    #pragma unroll
    for (int j = 0; j < 8; ++j) {
      int row = w * 16 + j * 2 + rj;
      int gq = (qq & 24) | ((qq & 7) ^ (row & 7));
      gload_lds16(ehi + (size_t)(nc + row) * EDIM + gq * 8,
                  &Bs[(w * 16 + j * 2) * 256]);
    }
  }

  // per-lane e2 and packed inverse-idx for its 8 columns
  float e2r[8];
  unsigned invc[8];
  #pragma unroll
  for (int n = 0; n < 8; ++n) {
    int c = nc + n * 16 + lr;
    e2r[n] = e2[c];
    invc[n] = (unsigned)(1023 - c);
  }

  __syncthreads();   // compiler drains vmcnt: B-tile ready. Last barrier in the kernel.

  bf16x8 A[2][8];
  {
    const int rowIt = rbase0 + w * 32;
    #pragma unroll
    for (int ms = 0; ms < 2; ++ms) {
      const unsigned short* zb = zhi + (size_t)(rowIt + ms * 16 + lr) * EDIM + q * 8;
      #pragma unroll
      for (int ks = 0; ks < 8; ++ks)
        A[ms][ks] = *(const bf16x8*)(zb + ks * 32);
    }
  }

  #pragma unroll
  for (int it = 0; it < 4; ++it) {
    const int rowIt = rbase0 + it * 256 + w * 32;
    f32x4 acc[2][8];
    #pragma unroll
    for (int ms = 0; ms < 2; ++ms)
      #pragma unroll
      for (int n = 0; n < 8; ++n)
        acc[ms][n] = (f32x4){0.f, 0.f, 0.f, 0.f};

    #pragma unroll
    for (int ks = 0; ks < 8; ++ks) {
      const int sq = ((ks * 4 + q) & 24) | (((ks * 4 + q) & 7) ^ (lr & 7));
      bf16x8 bfr[8];
      #pragma unroll
      for (int n = 0; n < 8; ++n)
        bfr[n] = *(const bf16x8*)&Bs[(n * 16 + lr) * 256 + sq * 8];
      #pragma unroll
      for (int n = 0; n < 8; ++n)
        #pragma unroll
        for (int ms = 0; ms < 2; ++ms)
          acc[ms][n] = __builtin_amdgcn_mfma_f32_16x16x32_bf16(A[ms][ks], bfr[n], acc[ms][n], 0, 0, 0);
    }

    if (it < 3) {   // A regs dead: load next iter's A; latency hides under epilogue
      const int rowN = rbase0 + (it + 1) * 256 + w * 32;
      #pragma unroll
      for (int ms = 0; ms < 2; ++ms) {
        const unsigned short* zb = zhi + (size_t)(rowN + ms * 16 + lr) * EDIM + q * 8;
        #pragma unroll
        for (int ks = 0; ks < 8; ++ks)
          A[ms][ks] = *(const bf16x8*)(zb + ks * 32);
      }
    }

    // epilogue: packed-key top2 over this iter's 32 rows x 128 cols (sim' = e2 - 2*dot)
    float b1[8], b2[8];
    #pragma unroll
    for (int s = 0; s < 8; ++s) { b1[s] = -3.4e38f; b2[s] = -3.4e38f; }
    #pragma unroll
    for (int n = 0; n < 8; ++n) {
      #pragma unroll
      for (int ms = 0; ms < 2; ++ms)
        #pragma unroll
        for (int r = 0; r < 4; ++r) {
          float sim = fmaf(acc[ms][n][r], -2.0f, e2r[n]);
          float key = __uint_as_float((__float_as_uint(sim) & 0xFFFFFC00u) | invc[n]);
          int s = ms * 4 + r;
          b2[s] = fmaxf(b2[s], fminf(b1[s], key));
          b1[s] = fmaxf(b1[s], key);
        }
    }
    // cross-lane top2-of-union over 16 col-lanes (masks 1,2,4,8): pure float max/min
    #pragma unroll
    for (int mask = 1; mask <= 8; mask <<= 1) {
      #pragma unroll
      for (int s = 0; s < 8; ++s) {
        float o1 = __shfl_xor(b1[s], mask);
        float o2 = __shfl_xor(b2[s], mask);
        b2[s] = fmaxf(fmaxf(b2[s], o2), fminf(b1[s], o1));
        b1[s] = fmaxf(b1[s], o1);
      }
    }
    if (lr == 0) {
      #pragma unroll
      for (int s = 0; s < 8; ++s) {
        int grow = rowIt + (s >> 2) * 16 + q * 4 + (s & 3);   // C-layout row = q*4+reg
        float2 t; t.x = b1[s]; t.y = b2[s];
        gtop[(size_t)grow * 8 + nstrip] = t;
      }
    }
  }
}

// ---------------- merge: packed-top2 union -> idxs + margin worklist + rowcnt reset -----
__global__ __launch_bounds__(256) void merge_kernel(const float2* __restrict__ gtop,
                                                    int* __restrict__ idxs,
                                                    int* __restrict__ cnt,
                                                    int* __restrict__ worklist,
                                                    int* __restrict__ rowcnt) {
  int r = blockIdx.x * 256 + threadIdx.x;   // grid 256 -> 65536 rows
  rowcnt[r] = 0;                            // quarter-done counter for fused merge2
  float b1 = -3.4e38f, b2 = -3.4e38f;
  #pragma unroll
  for (int s = 0; s < 8; ++s) {
    float2 t = gtop[(size_t)r * 8 + s];
    b2 = fmaxf(fmaxf(b2, t.y), fminf(b1, t.x));
    b1 = fmaxf(b1, t.x);
  }
  idxs[r] = 1023 - (int)(__float_as_uint(b1) & 1023u);
  if (b1 - b2 < MARGIN) {
    int p = atomicAdd(cnt, 1);
    worklist[p] = r;
  }
}

// ---------------- exact fp32 rescue, quarter-split + fused merge2 (last-quarter wins) ---
__global__ __launch_bounds__(256) void rescue_kernel(const float* __restrict__ z,
                                                     const float* __restrict__ embT,
                                                     const float* __restrict__ e2,
                                                     float2* __restrict__ ptop,
                                                     const int* __restrict__ cnt,
                                                     const int* __restrict__ worklist,
                                                     int* __restrict__ rowcnt,
                                                     int* __restrict__ idxs) {
  __shared__ float zr[16][EDIM];     // 16 KB
  __shared__ float z2s[16];
  __shared__ int   rows_s[16];
  const int tid = threadIdx.x;
  const int cg  = tid & 63;          // lane
  const int rg  = tid >> 6;          // wave
  const float4* z4 = (const float4*)z;
  const float4* eT4 = (const float4*)embT;
  const int n = cnt[0];
  const int nitems = ((n + 15) >> 4) << 2;

  for (int item = blockIdx.x; item < nitems; item += gridDim.x) {
    const int batch = item >> 2;
    const int quarter = item & 3;
    const int base = batch * 16;
    const int nr = min(16, n - base);

    __syncthreads();   // prior item's zr reads done before overwrite
    for (int i = tid; i < nr * 64; i += 256) {
      int r = i >> 6, k4 = i & 63;
      int row = worklist[base + r];
      ((float4*)zr[r])[k4] = z4[(size_t)row * 64 + k4];
    }
    if (tid < nr) rows_s[tid] = worklist[base + tid];
    __syncthreads();
    if (tid < nr) {    // per-row ||z||^2, R1-sequential rounding
      float s = 0.f;
      const float4* p = (const float4*)zr[tid];
      for (int k = 0; k < 64; ++k) {
        float4 v = p[k];
        s += v.x * v.x; s += v.y * v.y; s += v.z * v.z; s += v.w * v.w;
      }
      z2s[tid] = s;
    }
    __syncthreads();

    const int c0 = quarter * 256 + cg * 4;
    float dot[4][4];   // [cc][r]
    #pragma unroll
    for (int cc = 0; cc < 4; ++cc)
      #pragma unroll
      for (int r = 0; r < 4; ++r) dot[cc][r] = 0.f;

    for (int k4 = 0; k4 < 64; ++k4) {
      float4 a[4];
      #pragma unroll
      for (int r = 0; r < 4; ++r) a[r] = ((const float4*)zr[rg * 4 + r])[k4];  // bcast
      #pragma unroll
      for (int dk = 0; dk < 4; ++dk) {
        int k = k4 * 4 + dk;
        float4 b = eT4[(size_t)k * 256 + (c0 >> 2)];   // 1KB/wave coalesced
        #pragma unroll
        for (int r = 0; r < 4; ++r) {
          float av = (dk == 0) ? a[r].x : (dk == 1) ? a[r].y : (dk == 2) ? a[r].z : a[r].w;
          dot[0][r] = fmaf(av, b.x, dot[0][r]);
          dot[1][r] = fmaf(av, b.y, dot[1][r]);
          dot[2][r] = fmaf(av, b.z, dot[2][r]);
          dot[3][r] = fmaf(av, b.w, dot[3][r]);
        }
      }
    }

    float bv[4]; int bi[4];
    #pragma unroll
    for (int r = 0; r < 4; ++r) { bv[r] = -3.4e38f; bi[r] = 0; }
    #pragma unroll
    for (int cc = 0; cc < 4; ++cc) {
      int c = c0 + cc;
      float e2v = e2[c];
      #pragma unroll
      for (int r = 0; r < 4; ++r) {
        float t = z2s[rg * 4 + r] + e2v;
        float s = fmaf(dot[cc][r], -2.0f, t);
        if (s > bv[r] || (s == bv[r] && c < bi[r])) { bv[r] = s; bi[r] = c; }
      }
    }

    // in-wave reduce over 64 lanes (all lanes share rows rg*4..rg*4+3)
    #pragma unroll
    for (int mask = 1; mask <= 32; mask <<= 1) {
      #pragma unroll
      for (int r = 0; r < 4; ++r) {
        float ov = __shfl_xor(bv[r], mask);
        int   oi = __shfl_xor(bi[r], mask);
        if (ov > bv[r] || (ov == bv[r] && oi < bi[r])) { bv[r] = ov; bi[r] = oi; }
      }
    }
    if (cg == 0) {
      #pragma unroll
      for (int r = 0; r < 4; ++r) {
        int rr = rg * 4 + r;
        if (rr < nr) {
          int row = rows_s[rr];
          float2 t; t.x = bv[r]; t.y = __int_as_float(bi[r]);
          ptop[(size_t)row * 4 + quarter] = t;
          __threadfence();                          // publish ptop before counting
          int old = atomicAdd(&rowcnt[row], 1);
          if (old == 3) {                           // last quarter: fused merge2
            __threadfence();                        // acquire other quarters' ptop
            float mv = -3.4e38f; int mi = 0x7fffffff;
            #pragma unroll
            for (int qr = 0; qr < 4; ++qr) {
              float2 u = ptop[(size_t)row * 4 + qr];
              float v = u.x; int idx = __float_as_int(u.y);
              if (v > mv || (v == mv && idx < mi)) { mv = v; mi = idx; }
            }
            idxs[row] = mi;
          }
        }
      }
    }
  }
}

// ---------------- gather z_q + squared-diff partials + idxf + fused finalize ------------
__global__ __launch_bounds__(256) void gather_kernel(
    const float* __restrict__ z, const float* __restrict__ emb,
    const int* __restrict__ idxs, float* __restrict__ out,
    float* __restrict__ partials, float* __restrict__ idxf,
    int* __restrict__ gcnt) {
  const int tid = threadIdx.x;
  const int b = blockIdx.x;            // 1024 blocks, 64 rows each
  const float4* z4 = (const float4*)z;
  float4* q4 = (float4*)out;

  if (tid < 64) {
    int r2 = b * 64 + tid;
    idxf[r2] = (float)idxs[r2];
  }

  float acc = 0.f;
  #pragma unroll
  for (int i = 0; i < 16; ++i) {
    int f = b * 4096 + tid + 256 * i;  // float4 index
    int row = f >> 6;
    int c4 = f & 63;
    int e = idxs[row];
    float4 ev = *(const float4*)&emb[(size_t)e * EDIM + 4 * c4];
    float4 zv = z4[f];
    q4[f] = ev;
    float dx = ev.x - zv.x, dy = ev.y - zv.y, dz = ev.z - zv.z, dw = ev.w - zv.w;
    acc += dx * dx + dy * dy + dz * dz + dw * dw;
  }
  __shared__ float red[256];
  __shared__ int lastflag;
  red[tid] = acc;
  __syncthreads();
  #pragma unroll
  for (int sN = 128; sN > 0; sN >>= 1) {
    if (tid < sN) red[tid] += red[tid + sN];
    __syncthreads();
  }
  if (tid == 0) {
    partials[b] = red[0];
    __threadfence();                        // publish partial before counting
    int old = atomicAdd(gcnt, 1);
    lastflag = (old == 1023);
  }
  __syncthreads();
  if (lastflag) {                           // last block: fused finalize (R18 fp64 tree)
    __threadfence();                        // acquire all partials
    __shared__ double dred[256];
    float4 v = ((const float4*)partials)[tid];
    dred[tid] = (double)v.x + (double)v.y + (double)v.z + (double)v.w;
    __syncthreads();
    #pragma unroll
    for (int sN = 128; sN > 0; sN >>= 1) {
      if (tid < sN) dred[tid] += dred[tid + sN];   // fixed-order: deterministic
      __syncthreads();
    }
    if (tid == 0) {
      float m = (float)(dred[0] / 16777216.0);
      out[OUT_VQ] = m;
      out[OUT_CM] = 0.25f * m;
    }
  }
}

extern "C" void kernel_launch(void* const* d_in, const int* in_sizes, int n_in,
                              void* d_out, int out_size, void* d_ws, size_t ws_size,
                              hipStream_t stream) {
  const float* z   = (const float*)d_in[0];
  const float* emb = (const float*)d_in[1];
  float* out = (float*)d_out;

  // d_out z_q region (64MB) staging, overwritten by gather afterwards:
  //   zhi bf16 [0,32MB) | embT fp32 [32,33MB) | gtop float2 [36,40MB) | ptop [44,46MB)
  unsigned short* zhi = (unsigned short*)d_out;
  float* embT = out + 8388608;
  float2* gtop = (float2*)(out + 9437184);
  float2* ptop = (float2*)(out + 11534336);

  // ws: ehi 512KB | e2 4KB | idxs 256KB | partials 4KB | cnt 16B | worklist 256KB | rowcnt 256KB
  unsigned short* ehi = (unsigned short*)d_ws;
  float* e2       = (float*)(ehi + 262144);
  int*   idxs     = (int*)(e2 + 1024);
  float* partials = (float*)(idxs + 65536);
  int*   cnt      = (int*)(partials + 1024);
  int*   worklist = cnt + 4;
  int*   rowcnt   = worklist + 65536;

  zprep_kernel<<<8260, 256, 0, stream>>>(z, zhi, emb, ehi, e2, cnt, embT);
  argmax_kernel<<<512, 512, 0, stream>>>(zhi, ehi, e2, gtop);
  merge_kernel<<<256, 256, 0, stream>>>(gtop, idxs, cnt, worklist, rowcnt);
  rescue_kernel<<<2048, 256, 0, stream>>>(z, embT, e2, ptop, cnt, worklist, rowcnt, idxs);
  gather_kernel<<<1024, 256, 0, stream>>>(z, emb, idxs, out, partials, out + OUT_IDX, cnt + 1);
}

// Round 20
// 161.025 us; speedup vs baseline: 3.1289x; 3.1289x over previous
//
#include <hip/hip_runtime.h>

// VectorQuantizer: z [16,4096,256] f32, embedding [1024,256] f32
// out (f32, flat): z_q[16777216] | vq_loss[1] | commitment_loss[1] | idxs-as-float[65536]

#define ROWS 65536
#define EDIM 256
#define NEMB 1024
#define OUT_VQ  16777216
#define OUT_CM  16777217
#define OUT_IDX 16777218
#define MARGIN  0.8f

typedef __attribute__((ext_vector_type(8))) short bf16x8;
typedef __attribute__((ext_vector_type(4))) float f32x4;

__device__ inline unsigned short f2bf(float x) {
  unsigned u = __builtin_bit_cast(unsigned, x);
  unsigned r = (u + 0x7fff + ((u >> 16) & 1)) >> 16;
  return (unsigned short)r;
}
__device__ inline void gload_lds16(const void* g, void* l) {
  __builtin_amdgcn_global_load_lds((const __attribute__((address_space(1))) unsigned int*)g,
                                   (__attribute__((address_space(3))) unsigned int*)l,
                                   16, 0, 0);
}

// ---------------- zprep (fused): 0-8191 zsplit | 8192-8255 etrans | 8256-8259 eprep ----
__global__ __launch_bounds__(256) void zprep_kernel(const float* __restrict__ z,
                                                    unsigned short* __restrict__ zhi,
                                                    const float* __restrict__ emb,
                                                    unsigned short* __restrict__ ehi,
                                                    float* __restrict__ e2,
                                                    int* __restrict__ cnt,
                                                    float* __restrict__ embT) {
  __shared__ float tile[64][65];
  const int bid = blockIdx.x;
  if (bid < 8192) {
    // zsplit: z -> bf16 hi (validated body)
    size_t gid = (size_t)bid * 256 + threadIdx.x;
    const float4* z4 = (const float4*)z;
    float4 v0 = z4[gid * 2];
    float4 v1 = z4[gid * 2 + 1];
    uint4 ph;
    ph.x = (unsigned)f2bf(v0.x) | ((unsigned)f2bf(v0.y) << 16);
    ph.y = (unsigned)f2bf(v0.z) | ((unsigned)f2bf(v0.w) << 16);
    ph.z = (unsigned)f2bf(v1.x) | ((unsigned)f2bf(v1.y) << 16);
    ph.w = (unsigned)f2bf(v1.z) | ((unsigned)f2bf(v1.w) << 16);
    ((uint4*)zhi)[gid] = ph;
  } else if (bid < 8256) {
    // etrans: embT[k][c] = emb[c][k], 64x64 LDS tiles (validated body)
    const int bb = bid - 8192;
    const int bc = bb & 15;
    const int bk = bb >> 4;
    const int c0 = bc * 64, k0 = bk * 64;
    const int r = threadIdx.x >> 2;
    const int q = threadIdx.x & 3;
    #pragma unroll
    for (int j = 0; j < 4; ++j) {
      int kq = q + j * 4;
      float4 v = *(const float4*)&emb[(size_t)(c0 + r) * EDIM + k0 + kq * 4];
      tile[r][kq * 4 + 0] = v.x; tile[r][kq * 4 + 1] = v.y;
      tile[r][kq * 4 + 2] = v.z; tile[r][kq * 4 + 3] = v.w;
    }
    __syncthreads();
    #pragma unroll
    for (int j = 0; j < 4; ++j) {
      int cq = q + j * 4;
      float4 w;
      w.x = tile[cq * 4 + 0][r]; w.y = tile[cq * 4 + 1][r];
      w.z = tile[cq * 4 + 2][r]; w.w = tile[cq * 4 + 3][r];
      *(float4*)&embT[(size_t)(k0 + r) * NEMB + c0 + cq * 4] = w;
    }
  } else {
    // eprep: emb -> bf16 hi, e2 (R1 rounding order), cnt reset (validated body)
    int c = (bid - 8256) * 256 + threadIdx.x;
    if (c == 0) cnt[0] = 0;
    const float4* p = (const float4*)(emb + (size_t)c * EDIM);
    unsigned short* eh = ehi + (size_t)c * EDIM;
    float s = 0.f;
    #pragma unroll 8
    for (int j = 0; j < EDIM / 4; ++j) {
      float4 v = p[j];
      s += v.x * v.x; s += v.y * v.y; s += v.z * v.z; s += v.w * v.w;
      uint2 ph;
      ph.x = (unsigned)f2bf(v.x) | ((unsigned)f2bf(v.y) << 16);
      ph.y = (unsigned)f2bf(v.z) | ((unsigned)f2bf(v.w) << 16);
      *(uint2*)(eh + j * 4) = ph;
    }
    e2[c] = s;
  }
}

// ---------------- barrier-free strip argmax, mantissa-packed top-2 keys (validated) -----
__global__ __launch_bounds__(512) void argmax_kernel(
    const unsigned short* __restrict__ zhi, const unsigned short* __restrict__ ehi,
    const float* __restrict__ e2, float2* __restrict__ gtop) {
  __shared__ short Bs[128 * 256];   // 64 KB

  const int tid  = threadIdx.x;
  const int w    = tid >> 6;      // wave 0..7
  const int lane = tid & 63;
  const int q    = lane >> 4;     // 0..3
  const int lr   = lane & 15;
  const int b = blockIdx.x;
  const int mchunk = b & 63;
  const int nstrip = b >> 6;
  const int nc = nstrip * 128;
  const int rbase0 = mchunk * 1024;

  // ---- stage B once: instr j writes rows {w*16+j*2, +1} linearly; src pre-swizzled ----
  {
    const int qq = lane & 31;            // quad within row
    const int rj = lane >> 5;            // row within pair
    #pragma unroll
    for (int j = 0; j < 8; ++j) {
      int row = w * 16 + j * 2 + rj;
      int gq = (qq & 24) | ((qq & 7) ^ (row & 7));
      gload_lds16(ehi + (size_t)(nc + row) * EDIM + gq * 8,
                  &Bs[(w * 16 + j * 2) * 256]);
    }
  }

  // per-lane e2 and packed inverse-idx for its 8 columns
  float e2r[8];
  unsigned invc[8];
  #pragma unroll
  for (int n = 0; n < 8; ++n) {
    int c = nc + n * 16 + lr;
    e2r[n] = e2[c];
    invc[n] = (unsigned)(1023 - c);
  }

  __syncthreads();   // compiler drains vmcnt: B-tile ready. Last barrier in the kernel.

  bf16x8 A[2][8];
  {
    const int rowIt = rbase0 + w * 32;
    #pragma unroll
    for (int ms = 0; ms < 2; ++ms) {
      const unsigned short* zb = zhi + (size_t)(rowIt + ms * 16 + lr) * EDIM + q * 8;
      #pragma unroll
      for (int ks = 0; ks < 8; ++ks)
        A[ms][ks] = *(const bf16x8*)(zb + ks * 32);
    }
  }

  #pragma unroll
  for (int it = 0; it < 4; ++it) {
    const int rowIt = rbase0 + it * 256 + w * 32;
    f32x4 acc[2][8];
    #pragma unroll
    for (int ms = 0; ms < 2; ++ms)
      #pragma unroll
      for (int n = 0; n < 8; ++n)
        acc[ms][n] = (f32x4){0.f, 0.f, 0.f, 0.f};

    #pragma unroll
    for (int ks = 0; ks < 8; ++ks) {
      const int sq = ((ks * 4 + q) & 24) | (((ks * 4 + q) & 7) ^ (lr & 7));
      bf16x8 bfr[8];
      #pragma unroll
      for (int n = 0; n < 8; ++n)
        bfr[n] = *(const bf16x8*)&Bs[(n * 16 + lr) * 256 + sq * 8];
      #pragma unroll
      for (int n = 0; n < 8; ++n)
        #pragma unroll
        for (int ms = 0; ms < 2; ++ms)
          acc[ms][n] = __builtin_amdgcn_mfma_f32_16x16x32_bf16(A[ms][ks], bfr[n], acc[ms][n], 0, 0, 0);
    }

    if (it < 3) {   // A regs dead: load next iter's A; latency hides under epilogue
      const int rowN = rbase0 + (it + 1) * 256 + w * 32;
      #pragma unroll
      for (int ms = 0; ms < 2; ++ms) {
        const unsigned short* zb = zhi + (size_t)(rowN + ms * 16 + lr) * EDIM + q * 8;
        #pragma unroll
        for (int ks = 0; ks < 8; ++ks)
          A[ms][ks] = *(const bf16x8*)(zb + ks * 32);
      }
    }

    // epilogue: packed-key top2 over this iter's 32 rows x 128 cols (sim' = e2 - 2*dot)
    float b1[8], b2[8];
    #pragma unroll
    for (int s = 0; s < 8; ++s) { b1[s] = -3.4e38f; b2[s] = -3.4e38f; }
    #pragma unroll
    for (int n = 0; n < 8; ++n) {
      #pragma unroll
      for (int ms = 0; ms < 2; ++ms)
        #pragma unroll
        for (int r = 0; r < 4; ++r) {
          float sim = fmaf(acc[ms][n][r], -2.0f, e2r[n]);
          float key = __uint_as_float((__float_as_uint(sim) & 0xFFFFFC00u) | invc[n]);
          int s = ms * 4 + r;
          b2[s] = fmaxf(b2[s], fminf(b1[s], key));
          b1[s] = fmaxf(b1[s], key);
        }
    }
    // cross-lane top2-of-union over 16 col-lanes (masks 1,2,4,8): pure float max/min
    #pragma unroll
    for (int mask = 1; mask <= 8; mask <<= 1) {
      #pragma unroll
      for (int s = 0; s < 8; ++s) {
        float o1 = __shfl_xor(b1[s], mask);
        float o2 = __shfl_xor(b2[s], mask);
        b2[s] = fmaxf(fmaxf(b2[s], o2), fminf(b1[s], o1));
        b1[s] = fmaxf(b1[s], o1);
      }
    }
    if (lr == 0) {
      #pragma unroll
      for (int s = 0; s < 8; ++s) {
        int grow = rowIt + (s >> 2) * 16 + q * 4 + (s & 3);   // C-layout row = q*4+reg
        float2 t; t.x = b1[s]; t.y = b2[s];
        gtop[(size_t)grow * 8 + nstrip] = t;
      }
    }
  }
}

// ---------------- merge 8 strip packed-top2s -> idxs + margin worklist (validated) ------
__global__ __launch_bounds__(256) void merge_kernel(const float2* __restrict__ gtop,
                                                    int* __restrict__ idxs,
                                                    int* __restrict__ cnt,
                                                    int* __restrict__ worklist) {
  int r = blockIdx.x * 256 + threadIdx.x;   // grid 256 -> 65536 rows
  float b1 = -3.4e38f, b2 = -3.4e38f;
  #pragma unroll
  for (int s = 0; s < 8; ++s) {
    float2 t = gtop[(size_t)r * 8 + s];
    b2 = fmaxf(fmaxf(b2, t.y), fminf(b1, t.x));
    b1 = fmaxf(b1, t.x);
  }
  idxs[r] = 1023 - (int)(__float_as_uint(b1) & 1023u);
  if (b1 - b2 < MARGIN) {
    int p = atomicAdd(cnt, 1);
    worklist[p] = r;
  }
}

// ---------------- exact fp32 rescue, quarter-split (validated) --------------------------
__global__ __launch_bounds__(256) void rescue_kernel(const float* __restrict__ z,
                                                     const float* __restrict__ embT,
                                                     const float* __restrict__ e2,
                                                     float2* __restrict__ ptop,
                                                     const int* __restrict__ cnt,
                                                     const int* __restrict__ worklist) {
  __shared__ float zr[16][EDIM];     // 16 KB
  __shared__ float z2s[16];
  __shared__ int   rows_s[16];
  const int tid = threadIdx.x;
  const int cg  = tid & 63;          // lane
  const int rg  = tid >> 6;          // wave
  const float4* z4 = (const float4*)z;
  const float4* eT4 = (const float4*)embT;
  const int n = cnt[0];
  const int nitems = ((n + 15) >> 4) << 2;

  for (int item = blockIdx.x; item < nitems; item += gridDim.x) {
    const int batch = item >> 2;
    const int quarter = item & 3;
    const int base = batch * 16;
    const int nr = min(16, n - base);

    __syncthreads();   // prior item's zr reads done before overwrite
    for (int i = tid; i < nr * 64; i += 256) {
      int r = i >> 6, k4 = i & 63;
      int row = worklist[base + r];
      ((float4*)zr[r])[k4] = z4[(size_t)row * 64 + k4];
    }
    if (tid < nr) rows_s[tid] = worklist[base + tid];
    __syncthreads();
    if (tid < nr) {    // per-row ||z||^2, R1-sequential rounding
      float s = 0.f;
      const float4* p = (const float4*)zr[tid];
      for (int k = 0; k < 64; ++k) {
        float4 v = p[k];
        s += v.x * v.x; s += v.y * v.y; s += v.z * v.z; s += v.w * v.w;
      }
      z2s[tid] = s;
    }
    __syncthreads();

    const int c0 = quarter * 256 + cg * 4;
    float dot[4][4];   // [cc][r]
    #pragma unroll
    for (int cc = 0; cc < 4; ++cc)
      #pragma unroll
      for (int r = 0; r < 4; ++r) dot[cc][r] = 0.f;

    for (int k4 = 0; k4 < 64; ++k4) {
      float4 a[4];
      #pragma unroll
      for (int r = 0; r < 4; ++r) a[r] = ((const float4*)zr[rg * 4 + r])[k4];  // bcast
      #pragma unroll
      for (int dk = 0; dk < 4; ++dk) {
        int k = k4 * 4 + dk;
        float4 b = eT4[(size_t)k * 256 + (c0 >> 2)];   // 1KB/wave coalesced
        #pragma unroll
        for (int r = 0; r < 4; ++r) {
          float av = (dk == 0) ? a[r].x : (dk == 1) ? a[r].y : (dk == 2) ? a[r].z : a[r].w;
          dot[0][r] = fmaf(av, b.x, dot[0][r]);
          dot[1][r] = fmaf(av, b.y, dot[1][r]);
          dot[2][r] = fmaf(av, b.z, dot[2][r]);
          dot[3][r] = fmaf(av, b.w, dot[3][r]);
        }
      }
    }

    float bv[4]; int bi[4];
    #pragma unroll
    for (int r = 0; r < 4; ++r) { bv[r] = -3.4e38f; bi[r] = 0; }
    #pragma unroll
    for (int cc = 0; cc < 4; ++cc) {
      int c = c0 + cc;
      float e2v = e2[c];
      #pragma unroll
      for (int r = 0; r < 4; ++r) {
        float t = z2s[rg * 4 + r] + e2v;
        float s = fmaf(dot[cc][r], -2.0f, t);
        if (s > bv[r] || (s == bv[r] && c < bi[r])) { bv[r] = s; bi[r] = c; }
      }
    }

    // in-wave reduce over 64 lanes (all lanes share rows rg*4..rg*4+3)
    #pragma unroll
    for (int mask = 1; mask <= 32; mask <<= 1) {
      #pragma unroll
      for (int r = 0; r < 4; ++r) {
        float ov = __shfl_xor(bv[r], mask);
        int   oi = __shfl_xor(bi[r], mask);
        if (ov > bv[r] || (ov == bv[r] && oi < bi[r])) { bv[r] = ov; bi[r] = oi; }
      }
    }
    if (cg == 0) {
      #pragma unroll
      for (int r = 0; r < 4; ++r) {
        int rr = rg * 4 + r;
        if (rr < nr) {
          float2 t; t.x = bv[r]; t.y = __int_as_float(bi[r]);
          ptop[(size_t)rows_s[rr] * 4 + quarter] = t;
        }
      }
    }
  }
}

// ---------------- merge2: exact cross-quarter argmax for flagged rows ------------------
__global__ __launch_bounds__(256) void merge2_kernel(const float2* __restrict__ ptop,
                                                     int* __restrict__ idxs,
                                                     const int* __restrict__ cnt,
                                                     const int* __restrict__ worklist) {
  int i = blockIdx.x * 256 + threadIdx.x;   // grid 256 covers 65536
  if (i >= cnt[0]) return;
  int row = worklist[i];
  float bv = -3.4e38f; int bi = 0x7fffffff;
  #pragma unroll
  for (int qr = 0; qr < 4; ++qr) {
    float2 t = ptop[(size_t)row * 4 + qr];
    float v = t.x; int idx = __float_as_int(t.y);
    if (v > bv || (v == bv && idx < bi)) { bv = v; bi = idx; }
  }
  idxs[row] = bi;
}

// ---------------- gather z_q + squared-diff partial sums + idxf ----------------
__global__ __launch_bounds__(256) void gather_kernel(
    const float* __restrict__ z, const float* __restrict__ emb,
    const int* __restrict__ idxs, float* __restrict__ out,
    float* __restrict__ partials, float* __restrict__ idxf) {
  const int tid = threadIdx.x;
  const int b = blockIdx.x;            // 1024 blocks, 64 rows each
  const float4* z4 = (const float4*)z;
  float4* q4 = (float4*)out;

  if (tid < 64) {
    int r2 = b * 64 + tid;
    idxf[r2] = (float)idxs[r2];
  }

  float acc = 0.f;
  #pragma unroll
  for (int i = 0; i < 16; ++i) {
    int f = b * 4096 + tid + 256 * i;  // float4 index
    int row = f >> 6;
    int c4 = f & 63;
    int e = idxs[row];
    float4 ev = *(const float4*)&emb[(size_t)e * EDIM + 4 * c4];
    float4 zv = z4[f];
    q4[f] = ev;
    float dx = ev.x - zv.x, dy = ev.y - zv.y, dz = ev.z - zv.z, dw = ev.w - zv.w;
    acc += dx * dx + dy * dy + dz * dz + dw * dw;
  }
  __shared__ float red[256];
  red[tid] = acc;
  __syncthreads();
  #pragma unroll
  for (int sN = 128; sN > 0; sN >>= 1) {
    if (tid < sN) red[tid] += red[tid + sN];
    __syncthreads();
  }
  if (tid == 0) partials[b] = red[0];
}

// ---------------- finalize: parallel deterministic fp64 tree (validated) ----------------
__global__ __launch_bounds__(256) void finalize_kernel(const float* __restrict__ partials,
                                                       float* __restrict__ out) {
  __shared__ double red[256];
  const int tid = threadIdx.x;
  float4 v = ((const float4*)partials)[tid];
  double s = (double)v.x + (double)v.y + (double)v.z + (double)v.w;
  red[tid] = s;
  __syncthreads();
  #pragma unroll
  for (int sN = 128; sN > 0; sN >>= 1) {
    if (tid < sN) red[tid] += red[tid + sN];   // fixed-order pairwise: deterministic
    __syncthreads();
  }
  if (tid == 0) {
    float m = (float)(red[0] / 16777216.0);
    out[OUT_VQ] = m;
    out[OUT_CM] = 0.25f * m;
  }
}

extern "C" void kernel_launch(void* const* d_in, const int* in_sizes, int n_in,
                              void* d_out, int out_size, void* d_ws, size_t ws_size,
                              hipStream_t stream) {
  const float* z   = (const float*)d_in[0];
  const float* emb = (const float*)d_in[1];
  float* out = (float*)d_out;

  // d_out z_q region (64MB) staging, overwritten by gather afterwards:
  //   zhi bf16 [0,32MB) | embT fp32 [32,33MB) | gtop float2 [36,40MB) | ptop [44,46MB)
  unsigned short* zhi = (unsigned short*)d_out;
  float* embT = out + 8388608;
  float2* gtop = (float2*)(out + 9437184);
  float2* ptop = (float2*)(out + 11534336);

  // ws: ehi 512KB | e2 4KB | idxs 256KB | partials 4KB | cnt 16B | worklist 256KB
  unsigned short* ehi = (unsigned short*)d_ws;
  float* e2       = (float*)(ehi + 262144);
  int*   idxs     = (int*)(e2 + 1024);
  float* partials = (float*)(idxs + 65536);
  int*   cnt      = (int*)(partials + 1024);
  int*   worklist = cnt + 4;

  zprep_kernel<<<8260, 256, 0, stream>>>(z, zhi, emb, ehi, e2, cnt, embT);
  argmax_kernel<<<512, 512, 0, stream>>>(zhi, ehi, e2, gtop);
  merge_kernel<<<256, 256, 0, stream>>>(gtop, idxs, cnt, worklist);
  rescue_kernel<<<2048, 256, 0, stream>>>(z, embT, e2, ptop, cnt, worklist);
  merge2_kernel<<<256, 256, 0, stream>>>(ptop, idxs, cnt, worklist);
  gather_kernel<<<1024, 256, 0, stream>>>(z, emb, idxs, out, partials, out + OUT_IDX);
  finalize_kernel<<<1, 256, 0, stream>>>(partials, out);
}